// Round 1
// baseline (724.559 us; speedup 1.0000x reference)
//
#include <hip/hip_runtime.h>
#include <hip/hip_bf16.h>
#include <math.h>

#define NNODE 20000
#define FIN   128
#define HC    256     // HEADS*HID
#define HEADS 8
#define HID   32
#define NEDGE 320000
#define ETOT  (NEDGE + NNODE)
#define NGRAPH 64
#define NCLS  10

// ---------------- CSR build ----------------

__global__ void build_deg(const int* __restrict__ ei, int* __restrict__ deg) {
    int e = blockIdx.x * blockDim.x + threadIdx.x;
    if (e >= ETOT) return;
    int dst = (e < NEDGE) ? ei[NEDGE + e] : (e - NEDGE);
    atomicAdd(&deg[dst], 1);
}

__global__ void scan_excl(const int* __restrict__ in, int* __restrict__ out, int n) {
    __shared__ int sm[1024];
    __shared__ int carry;
    if (threadIdx.x == 0) carry = 0;
    __syncthreads();
    for (int base = 0; base < n; base += 1024) {
        int i = base + (int)threadIdx.x;
        int v = (i < n) ? in[i] : 0;
        sm[threadIdx.x] = v;
        __syncthreads();
        for (int s = 1; s < 1024; s <<= 1) {
            int t = (threadIdx.x >= (unsigned)s) ? sm[threadIdx.x - s] : 0;
            __syncthreads();
            sm[threadIdx.x] += t;
            __syncthreads();
        }
        if (i < n) out[i] = carry + sm[threadIdx.x] - v;   // exclusive
        __syncthreads();
        if (threadIdx.x == 0) carry += sm[1023];
        __syncthreads();
    }
    if (threadIdx.x == 0) out[n] = carry;
}

__global__ void scatter_edges(const int* __restrict__ ei, const int* __restrict__ off,
                              int* __restrict__ cursor, int* __restrict__ esrc) {
    int e = blockIdx.x * blockDim.x + threadIdx.x;
    if (e >= ETOT) return;
    int src, dst;
    if (e < NEDGE) { src = ei[e]; dst = ei[NEDGE + e]; }
    else           { src = e - NEDGE; dst = src; }
    int pos = off[dst] + atomicAdd(&cursor[dst], 1);
    esrc[pos] = src;
}

// ---------------- fp32 tiled GEMM: C[M,Nn] = A[M,K] @ W[K,Nn] ----------------
// 64x64 tile per block (16x16 threads, 4x4 per thread), K-tile 16.

__global__ __launch_bounds__(256) void gemm_fp32(const float* __restrict__ A,
                                                 const float* __restrict__ W,
                                                 float* __restrict__ C,
                                                 int M, int K, int Nn) {
    __shared__ float As[16][64];   // [kk][row]
    __shared__ float Bs[16][64];   // [kk][col]
    int tx = threadIdx.x & 15;
    int ty = threadIdx.x >> 4;
    int rowBase = blockIdx.x * 64;
    int colBase = blockIdx.y * 64;
    float acc[4][4] = {};
    for (int k0 = 0; k0 < K; k0 += 16) {
        int t = threadIdx.x;
        #pragma unroll
        for (int q = 0; q < 4; q++) {
            int idx = t * 4 + q;        // 0..1023
            int r  = idx >> 4;
            int kk = idx & 15;
            int grow = rowBase + r;
            As[kk][r] = (grow < M) ? A[(long)grow * K + k0 + kk] : 0.f;
        }
        #pragma unroll
        for (int q = 0; q < 4; q++) {
            int idx = t * 4 + q;
            int kk = idx >> 6;
            int c  = idx & 63;
            Bs[kk][c] = W[(long)(k0 + kk) * Nn + colBase + c];
        }
        __syncthreads();
        #pragma unroll
        for (int kk = 0; kk < 16; kk++) {
            float a[4], b[4];
            #pragma unroll
            for (int i = 0; i < 4; i++) a[i] = As[kk][ty * 4 + i];
            #pragma unroll
            for (int j = 0; j < 4; j++) b[j] = Bs[kk][tx * 4 + j];
            #pragma unroll
            for (int i = 0; i < 4; i++)
                #pragma unroll
                for (int j = 0; j < 4; j++)
                    acc[i][j] += a[i] * b[j];
        }
        __syncthreads();
    }
    #pragma unroll
    for (int i = 0; i < 4; i++) {
        int r = rowBase + ty * 4 + i;
        if (r < M) {
            #pragma unroll
            for (int j = 0; j < 4; j++)
                C[(long)r * Nn + colBase + tx * 4 + j] = acc[i][j];
        }
    }
}

// ---------------- per-node attention scalars: aL[n,h]=h(n)·att_l(h), aR likewise ----

__global__ void node_alpha(const float* __restrict__ h, const float* __restrict__ attL,
                           const float* __restrict__ attR, float* __restrict__ aL,
                           float* __restrict__ aR) {
    int node = blockIdx.x;
    int t = threadIdx.x;                 // t = head*32 + c, matches flat (8,32)
    float hv = h[node * HC + t];
    float pl = hv * attL[t];
    float pr = hv * attR[t];
    #pragma unroll
    for (int s = 16; s; s >>= 1) {
        pl += __shfl_xor(pl, s);
        pr += __shfl_xor(pr, s);
    }
    if ((t & 31) == 0) {
        int head = t >> 5;
        aL[node * HEADS + head] = pl;
        aR[node * HEADS + head] = pr;
    }
}

// ---------------- per-dst-node attention + aggregate (online softmax) ----------------
// block = 256 threads = one feature each; head = t>>5 (32 lanes per head, within wave)

__global__ __launch_bounds__(256) void attn_aggregate(const float* __restrict__ h,
                                                      const int* __restrict__ off,
                                                      const int* __restrict__ esrc,
                                                      const float* __restrict__ aL,
                                                      const float* __restrict__ aR,
                                                      const float* __restrict__ bias,
                                                      float* __restrict__ out,
                                                      int apply_elu) {
    int i = blockIdx.x;
    int t = threadIdx.x;
    int head = t >> 5;
    float hi = h[i * HC + t];
    float a_ri = aR[i * HEADS + head];
    int beg = off[i], end = off[i + 1];
    float m = -1e30f, l = 0.f, acc = 0.f;
    for (int p = beg; p < end; ++p) {
        int j = esrc[p];
        float hj = h[j * HC + t];
        float prod = hi * hj;
        #pragma unroll
        for (int s = 16; s; s >>= 1) prod += __shfl_xor(prod, s);  // dot over 32 chans
        float logit = prod;
        float alpha = aL[j * HEADS + head] + a_ri;
        alpha = alpha / (1.f + expf(-logit));          // * sigmoid(logit)
        alpha = (alpha > 0.f) ? alpha : 0.2f * alpha;  // leaky_relu 0.2
        float mn = fmaxf(m, alpha);
        float scale = expf(m - mn);
        float ex = expf(alpha - mn);
        l = l * scale + ex;
        acc = acc * scale + ex * hj;
        m = mn;
    }
    float r = acc / (l + 1e-16f) + bias[t];
    if (apply_elu) r = (r > 0.f) ? r : (expf(r) - 1.f);
    out[i * HC + t] = r;
}

// ---------------- pooling + head ----------------

__global__ void pool_kernel(const float* __restrict__ h, const int* __restrict__ batch,
                            float* __restrict__ psum, float* __restrict__ pcnt) {
    int node = blockIdx.x;
    int t = threadIdx.x;
    int g = batch[node];
    atomicAdd(&psum[g * HC + t], h[node * HC + t]);
    if (t == 0) atomicAdd(&pcnt[g], 1.f);
}

__global__ void final_kernel(const float* __restrict__ psum, const float* __restrict__ pcnt,
                             const float* __restrict__ linW, const float* __restrict__ linb,
                             float* __restrict__ out) {
    int g = blockIdx.x;
    int t = threadIdx.x;
    __shared__ float p[HC];
    float c = fmaxf(pcnt[g], 1.f);
    p[t] = psum[g * HC + t] / c;
    __syncthreads();
    if (t < NCLS) {
        float s = linb[t];
        for (int cch = 0; cch < HC; cch++) s += p[cch] * linW[cch * NCLS + t];
        out[g * NCLS + t] = s;
    }
}

// ---------------- launch ----------------

extern "C" void kernel_launch(void* const* d_in, const int* in_sizes, int n_in,
                              void* d_out, int out_size, void* d_ws, size_t ws_size,
                              hipStream_t stream) {
    const float* x     = (const float*)d_in[0];
    const int*   ei    = (const int*)d_in[1];
    const int*   batch = (const int*)d_in[2];
    const float* W1    = (const float*)d_in[3];
    const float* attL1 = (const float*)d_in[4];
    const float* attR1 = (const float*)d_in[5];
    const float* b1    = (const float*)d_in[6];
    const float* W2    = (const float*)d_in[7];
    const float* attL2 = (const float*)d_in[8];
    const float* attR2 = (const float*)d_in[9];
    const float* b2    = (const float*)d_in[10];
    const float* linW  = (const float*)d_in[11];
    const float* linb  = (const float*)d_in[12];
    float* out = (float*)d_out;

    // workspace layout
    char* w = (char*)d_ws;
    size_t o = 0;
    int* deg    = (int*)(w + o); o += (size_t)NNODE * 4;
    int* cursor = (int*)(w + o); o += (size_t)NNODE * 4;
    int* off    = (int*)(w + o); o += (size_t)(NNODE + 1) * 4;
    o = (o + 15) & ~(size_t)15;
    int* esrc   = (int*)(w + o); o += (size_t)ETOT * 4;
    o = (o + 15) & ~(size_t)15;
    float* bufA = (float*)(w + o); o += (size_t)NNODE * HC * 4;
    float* bufB = (float*)(w + o); o += (size_t)NNODE * HC * 4;
    float* aL   = (float*)(w + o); o += (size_t)NNODE * HEADS * 4;
    float* aR   = (float*)(w + o); o += (size_t)NNODE * HEADS * 4;
    float* psum = (float*)(w + o); o += (size_t)NGRAPH * HC * 4;
    float* pcnt = (float*)(w + o); o += (size_t)NGRAPH * 4;

    // zero: deg+cursor contiguous; psum+pcnt contiguous
    hipMemsetAsync(deg, 0, (size_t)2 * NNODE * 4, stream);
    hipMemsetAsync(psum, 0, (size_t)(NGRAPH * HC + NGRAPH) * 4, stream);

    int eb = (ETOT + 255) / 256;
    build_deg<<<eb, 256, 0, stream>>>(ei, deg);
    scan_excl<<<1, 1024, 0, stream>>>(deg, off, NNODE);
    scatter_edges<<<eb, 256, 0, stream>>>(ei, off, cursor, esrc);

    dim3 g1((NNODE + 63) / 64, HC / 64);
    // layer 1
    gemm_fp32<<<g1, 256, 0, stream>>>(x, W1, bufA, NNODE, FIN, HC);
    node_alpha<<<NNODE, 256, 0, stream>>>(bufA, attL1, attR1, aL, aR);
    attn_aggregate<<<NNODE, 256, 0, stream>>>(bufA, off, esrc, aL, aR, b1, bufB, 1);
    // layer 2
    gemm_fp32<<<g1, 256, 0, stream>>>(bufB, W2, bufA, NNODE, HC, HC);
    node_alpha<<<NNODE, 256, 0, stream>>>(bufA, attL2, attR2, aL, aR);
    attn_aggregate<<<NNODE, 256, 0, stream>>>(bufA, off, esrc, aL, aR, b2, bufB, 0);
    // pool + head
    pool_kernel<<<NNODE, 256, 0, stream>>>(bufB, batch, psum, pcnt);
    final_kernel<<<NGRAPH, 256, 0, stream>>>(psum, pcnt, linW, linb, out);
}

// Round 2
// 387.272 us; speedup vs baseline: 1.8709x; 1.8709x over previous
//
#include <hip/hip_runtime.h>
#include <hip/hip_bf16.h>
#include <math.h>

#define NNODE 20000
#define FIN   128
#define HC    256     // HEADS*HID
#define HEADS 8
#define HID   32
#define NEDGE 320000
#define ETOT  (NEDGE + NNODE)
#define NGRAPH 64
#define NCLS  10

// ---------------- CSR build ----------------

__global__ void build_deg(const int* __restrict__ ei, int* __restrict__ deg) {
    int e = blockIdx.x * blockDim.x + threadIdx.x;
    if (e >= ETOT) return;
    int dst = (e < NEDGE) ? ei[NEDGE + e] : (e - NEDGE);
    atomicAdd(&deg[dst], 1);
}

__global__ void scan_excl(const int* __restrict__ in, int* __restrict__ out, int n) {
    __shared__ int sm[1024];
    __shared__ int carry;
    if (threadIdx.x == 0) carry = 0;
    __syncthreads();
    for (int base = 0; base < n; base += 1024) {
        int i = base + (int)threadIdx.x;
        int v = (i < n) ? in[i] : 0;
        sm[threadIdx.x] = v;
        __syncthreads();
        for (int s = 1; s < 1024; s <<= 1) {
            int t = (threadIdx.x >= (unsigned)s) ? sm[threadIdx.x - s] : 0;
            __syncthreads();
            sm[threadIdx.x] += t;
            __syncthreads();
        }
        if (i < n) out[i] = carry + sm[threadIdx.x] - v;   // exclusive
        __syncthreads();
        if (threadIdx.x == 0) carry += sm[1023];
        __syncthreads();
    }
    if (threadIdx.x == 0) out[n] = carry;
}

__global__ void scatter_edges(const int* __restrict__ ei, const int* __restrict__ off,
                              int* __restrict__ cursor, int* __restrict__ esrc) {
    int e = blockIdx.x * blockDim.x + threadIdx.x;
    if (e >= ETOT) return;
    int src, dst;
    if (e < NEDGE) { src = ei[e]; dst = ei[NEDGE + e]; }
    else           { src = e - NEDGE; dst = src; }
    int pos = off[dst] + atomicAdd(&cursor[dst], 1);
    esrc[pos] = src;
}

// ---------------- fp32 tiled GEMM: C[M,Nn] = A[M,K] @ W[K,Nn] ----------------

__global__ __launch_bounds__(256) void gemm_fp32(const float* __restrict__ A,
                                                 const float* __restrict__ W,
                                                 float* __restrict__ C,
                                                 int M, int K, int Nn) {
    __shared__ float As[16][64];   // [kk][row]
    __shared__ float Bs[16][64];   // [kk][col]
    int tx = threadIdx.x & 15;
    int ty = threadIdx.x >> 4;
    int rowBase = blockIdx.x * 64;
    int colBase = blockIdx.y * 64;
    float acc[4][4] = {};
    for (int k0 = 0; k0 < K; k0 += 16) {
        int t = threadIdx.x;
        #pragma unroll
        for (int q = 0; q < 4; q++) {
            int idx = t * 4 + q;        // 0..1023
            int r  = idx >> 4;
            int kk = idx & 15;
            int grow = rowBase + r;
            As[kk][r] = (grow < M) ? A[(long)grow * K + k0 + kk] : 0.f;
        }
        #pragma unroll
        for (int q = 0; q < 4; q++) {
            int idx = t * 4 + q;
            int kk = idx >> 6;
            int c  = idx & 63;
            Bs[kk][c] = W[(long)(k0 + kk) * Nn + colBase + c];
        }
        __syncthreads();
        #pragma unroll
        for (int kk = 0; kk < 16; kk++) {
            float a[4], b[4];
            #pragma unroll
            for (int i = 0; i < 4; i++) a[i] = As[kk][ty * 4 + i];
            #pragma unroll
            for (int j = 0; j < 4; j++) b[j] = Bs[kk][tx * 4 + j];
            #pragma unroll
            for (int i = 0; i < 4; i++)
                #pragma unroll
                for (int j = 0; j < 4; j++)
                    acc[i][j] += a[i] * b[j];
        }
        __syncthreads();
    }
    #pragma unroll
    for (int i = 0; i < 4; i++) {
        int r = rowBase + ty * 4 + i;
        if (r < M) {
            #pragma unroll
            for (int j = 0; j < 4; j++)
                C[(long)r * Nn + colBase + tx * 4 + j] = acc[i][j];
        }
    }
}

// ---------------- per-node attention scalars ----------------

__global__ void node_alpha(const float* __restrict__ h, const float* __restrict__ attL,
                           const float* __restrict__ attR, float* __restrict__ aL,
                           float* __restrict__ aR) {
    int node = blockIdx.x;
    int t = threadIdx.x;                 // t = head*32 + c, matches flat (8,32)
    float hv = h[node * HC + t];
    float pl = hv * attL[t];
    float pr = hv * attR[t];
    #pragma unroll
    for (int s = 16; s; s >>= 1) {
        pl += __shfl_xor(pl, s);
        pr += __shfl_xor(pr, s);
    }
    if ((t & 31) == 0) {
        int head = t >> 5;
        aL[node * HEADS + head] = pl;
        aR[node * HEADS + head] = pr;
    }
}

// ---------------- fused attention: 1 wave per dst node, 4 nodes/block ----------
// lane l owns channels 4l..4l+3 (float4); head = l>>3 (8 lanes per head).
// Single-pass online softmax with one exp per edge (plus one for sigmoid).

__global__ __launch_bounds__(256) void fused_attn(const float* __restrict__ h,
                                                  const int* __restrict__ off,
                                                  const int* __restrict__ esrc,
                                                  const float* __restrict__ aL,
                                                  const float* __restrict__ aR,
                                                  const float* __restrict__ bias,
                                                  float* __restrict__ out,
                                                  int apply_elu) {
    int wave = threadIdx.x >> 6;
    int node = blockIdx.x * 4 + wave;
    if (node >= NNODE) return;
    int l = threadIdx.x & 63;
    int head = l >> 3;
    const float4* h4 = (const float4*)h;

    float4 hi = h4[node * 64 + l];
    float a_ri = aR[node * HEADS + head];
    int beg = off[node], end = off[node + 1];

    float m = -1e30f, lsum = 0.f;
    float4 acc = {0.f, 0.f, 0.f, 0.f};

    int j = esrc[beg];
    for (int p = beg; p < end; ++p) {
        float4 hj = h4[j * 64 + l];
        float a_lj = aL[j * HEADS + head];
        // prefetch next edge index
        if (p + 1 < end) j = esrc[p + 1];
        // dot over this head's 32 channels: 4 per lane, butterfly over 8 lanes
        float prod = hi.x * hj.x + hi.y * hj.y + hi.z * hj.z + hi.w * hj.w;
        prod += __shfl_xor(prod, 1);
        prod += __shfl_xor(prod, 2);
        prod += __shfl_xor(prod, 4);
        float alpha = (a_lj + a_ri) / (1.f + __expf(-prod));   // * sigmoid(logit)
        alpha = (alpha > 0.f) ? alpha : 0.2f * alpha;          // leaky_relu 0.2
        // online softmax, single exp
        float mn = fmaxf(m, alpha);
        float e  = __expf(fminf(m, alpha) - mn);
        bool up = alpha > m;
        float scale = up ? e : 1.f;
        float ex    = up ? 1.f : e;
        lsum = lsum * scale + ex;
        acc.x = acc.x * scale + ex * hj.x;
        acc.y = acc.y * scale + ex * hj.y;
        acc.z = acc.z * scale + ex * hj.z;
        acc.w = acc.w * scale + ex * hj.w;
        m = mn;
    }
    float inv = 1.f / (lsum + 1e-16f);
    float4 b4 = ((const float4*)bias)[l];
    float4 r;
    r.x = acc.x * inv + b4.x;
    r.y = acc.y * inv + b4.y;
    r.z = acc.z * inv + b4.z;
    r.w = acc.w * inv + b4.w;
    if (apply_elu) {
        r.x = (r.x > 0.f) ? r.x : (__expf(r.x) - 1.f);
        r.y = (r.y > 0.f) ? r.y : (__expf(r.y) - 1.f);
        r.z = (r.z > 0.f) ? r.z : (__expf(r.z) - 1.f);
        r.w = (r.w > 0.f) ? r.w : (__expf(r.w) - 1.f);
    }
    ((float4*)out)[node * 64 + l] = r;
}

// ---------------- pooling (segmented, sorted batch) + head ----------------

__global__ __launch_bounds__(256) void pool_kernel(const float* __restrict__ h,
                                                   const int* __restrict__ batch,
                                                   float* __restrict__ psum,
                                                   float* __restrict__ pcnt) {
    int t = threadIdx.x;
    int n0 = blockIdx.x * 64;
    int n1 = min(n0 + 64, NNODE);
    if (n0 >= NNODE) return;
    float accv = 0.f;
    int gcur = batch[n0];
    for (int n = n0; n < n1; ++n) {
        int g = batch[n];
        if (g != gcur) {
            atomicAdd(&psum[gcur * HC + t], accv);
            accv = 0.f;
            gcur = g;
        }
        accv += h[n * HC + t];
    }
    atomicAdd(&psum[gcur * HC + t], accv);
    if (t == 0) {
        int cnt = 0;
        int gc = batch[n0];
        for (int n = n0; n < n1; ++n) {
            int g = batch[n];
            if (g != gc) { atomicAdd(&pcnt[gc], (float)cnt); cnt = 0; gc = g; }
            cnt++;
        }
        atomicAdd(&pcnt[gc], (float)cnt);
    }
}

__global__ void final_kernel(const float* __restrict__ psum, const float* __restrict__ pcnt,
                             const float* __restrict__ linW, const float* __restrict__ linb,
                             float* __restrict__ out) {
    int g = blockIdx.x;
    int t = threadIdx.x;
    __shared__ float p[HC];
    float c = fmaxf(pcnt[g], 1.f);
    p[t] = psum[g * HC + t] / c;
    __syncthreads();
    if (t < NCLS) {
        float s = linb[t];
        for (int cch = 0; cch < HC; cch++) s += p[cch] * linW[cch * NCLS + t];
        out[g * NCLS + t] = s;
    }
}

// ---------------- launch ----------------

extern "C" void kernel_launch(void* const* d_in, const int* in_sizes, int n_in,
                              void* d_out, int out_size, void* d_ws, size_t ws_size,
                              hipStream_t stream) {
    const float* x     = (const float*)d_in[0];
    const int*   ei    = (const int*)d_in[1];
    const int*   batch = (const int*)d_in[2];
    const float* W1    = (const float*)d_in[3];
    const float* attL1 = (const float*)d_in[4];
    const float* attR1 = (const float*)d_in[5];
    const float* b1    = (const float*)d_in[6];
    const float* W2    = (const float*)d_in[7];
    const float* attL2 = (const float*)d_in[8];
    const float* attR2 = (const float*)d_in[9];
    const float* b2    = (const float*)d_in[10];
    const float* linW  = (const float*)d_in[11];
    const float* linb  = (const float*)d_in[12];
    float* out = (float*)d_out;

    // workspace layout
    char* w = (char*)d_ws;
    size_t o = 0;
    int* deg    = (int*)(w + o); o += (size_t)NNODE * 4;
    int* cursor = (int*)(w + o); o += (size_t)NNODE * 4;
    int* off    = (int*)(w + o); o += (size_t)(NNODE + 1) * 4;
    o = (o + 15) & ~(size_t)15;
    int* esrc   = (int*)(w + o); o += (size_t)ETOT * 4;
    o = (o + 15) & ~(size_t)15;
    float* bufA = (float*)(w + o); o += (size_t)NNODE * HC * 4;
    float* bufB = (float*)(w + o); o += (size_t)NNODE * HC * 4;
    float* aL   = (float*)(w + o); o += (size_t)NNODE * HEADS * 4;
    float* aR   = (float*)(w + o); o += (size_t)NNODE * HEADS * 4;
    float* psum = (float*)(w + o); o += (size_t)NGRAPH * HC * 4;
    float* pcnt = (float*)(w + o); o += (size_t)NGRAPH * 4;

    hipMemsetAsync(deg, 0, (size_t)2 * NNODE * 4, stream);
    hipMemsetAsync(psum, 0, (size_t)(NGRAPH * HC + NGRAPH) * 4, stream);

    int eb = (ETOT + 255) / 256;
    build_deg<<<eb, 256, 0, stream>>>(ei, deg);
    scan_excl<<<1, 1024, 0, stream>>>(deg, off, NNODE);
    scatter_edges<<<eb, 256, 0, stream>>>(ei, off, cursor, esrc);

    dim3 g1((NNODE + 63) / 64, HC / 64);
    int ab = (NNODE + 3) / 4;
    // layer 1
    gemm_fp32<<<g1, 256, 0, stream>>>(x, W1, bufA, NNODE, FIN, HC);
    node_alpha<<<NNODE, 256, 0, stream>>>(bufA, attL1, attR1, aL, aR);
    fused_attn<<<ab, 256, 0, stream>>>(bufA, off, esrc, aL, aR, b1, bufB, 1);
    // layer 2
    gemm_fp32<<<g1, 256, 0, stream>>>(bufB, W2, bufA, NNODE, HC, HC);
    node_alpha<<<NNODE, 256, 0, stream>>>(bufA, attL2, attR2, aL, aR);
    fused_attn<<<ab, 256, 0, stream>>>(bufA, off, esrc, aL, aR, b2, bufB, 0);
    // pool + head
    pool_kernel<<<(NNODE + 63) / 64, 256, 0, stream>>>(bufB, batch, psum, pcnt);
    final_kernel<<<NGRAPH, 256, 0, stream>>>(psum, pcnt, linW, linb, out);
}

// Round 3
// 376.087 us; speedup vs baseline: 1.9266x; 1.0297x over previous
//
#include <hip/hip_runtime.h>
#include <hip/hip_bf16.h>
#include <math.h>

#define NNODE 20000
#define FIN   128
#define HC    256     // HEADS*HID
#define HEADS 8
#define HID   32
#define NEDGE 320000
#define ETOT  (NEDGE + NNODE)
#define NGRAPH 64
#define NCLS  10

#define SCAN_NB ((NNODE + 255) / 256)   // 79

// ---------------- CSR build ----------------

__global__ void build_deg(const int* __restrict__ ei, int* __restrict__ deg) {
    int e = blockIdx.x * blockDim.x + threadIdx.x;
    if (e >= ETOT) return;
    int dst = (e < NEDGE) ? ei[NEDGE + e] : (e - NEDGE);
    atomicAdd(&deg[dst], 1);
}

// pass 1: per-block exclusive scan, emit block sums
__global__ __launch_bounds__(256) void scan1(const int* __restrict__ deg,
                                             int* __restrict__ off,
                                             int* __restrict__ bsum) {
    __shared__ int sm[256];
    int i = blockIdx.x * 256 + threadIdx.x;
    int v = (i < NNODE) ? deg[i] : 0;
    sm[threadIdx.x] = v;
    __syncthreads();
    #pragma unroll
    for (int s = 1; s < 256; s <<= 1) {
        int t = (threadIdx.x >= (unsigned)s) ? sm[threadIdx.x - s] : 0;
        __syncthreads();
        sm[threadIdx.x] += t;
        __syncthreads();
    }
    if (i < NNODE) off[i] = sm[threadIdx.x] - v;   // exclusive within block
    if (threadIdx.x == 255) bsum[blockIdx.x] = sm[255];
}

// pass 2: scan the block sums (single small block)
__global__ __launch_bounds__(128) void scan2(const int* __restrict__ bsum,
                                             int* __restrict__ bscan,
                                             int* __restrict__ off) {
    __shared__ int sm[128];
    int t = threadIdx.x;
    int v = (t < SCAN_NB) ? bsum[t] : 0;
    sm[t] = v;
    __syncthreads();
    #pragma unroll
    for (int s = 1; s < 128; s <<= 1) {
        int u = (t >= (unsigned)s) ? sm[t - s] : 0;
        __syncthreads();
        sm[t] += u;
        __syncthreads();
    }
    if (t < SCAN_NB) bscan[t] = sm[t] - v;     // exclusive
    if (t == SCAN_NB - 1) off[NNODE] = sm[t];  // total
}

// pass 3: add block offsets
__global__ __launch_bounds__(256) void scan3(int* __restrict__ off,
                                             const int* __restrict__ bscan) {
    int i = blockIdx.x * 256 + threadIdx.x;
    if (i < NNODE) off[i] += bscan[blockIdx.x];
}

__global__ void scatter_edges(const int* __restrict__ ei, const int* __restrict__ off,
                              int* __restrict__ cursor, int* __restrict__ esrc) {
    int e = blockIdx.x * blockDim.x + threadIdx.x;
    if (e >= ETOT) return;
    int src, dst;
    if (e < NEDGE) { src = ei[e]; dst = ei[NEDGE + e]; }
    else           { src = e - NEDGE; dst = src; }
    int pos = off[dst] + atomicAdd(&cursor[dst], 1);
    esrc[pos] = src;
}

// ---------------- fp32 GEMM: C[M,Nn] = A[M,K] @ W[K,Nn]; 128x128 tile -------
// 256 threads, 8x8 acc/thread, K-tile 16, float4 LDS fragments.

__global__ __launch_bounds__(256) void gemm128(const float* __restrict__ A,
                                               const float* __restrict__ W,
                                               float* __restrict__ C,
                                               int M, int K, int Nn) {
    __shared__ float As[16][128];
    __shared__ float Bs[16][132];   // +4 pad: break staging-write bank conflicts
    int tid = threadIdx.x;
    int tx = tid & 15;
    int ty = tid >> 4;
    int rowBase = blockIdx.x * 128;
    int colBase = blockIdx.y * 128;
    float acc[8][8] = {};

    // staging roles
    int ar = tid >> 1;               // A row 0..127
    int ah = (tid & 1) * 8;          // A k-offset 0 or 8
    int bkk = tid >> 4;              // B k row 0..15
    int bc  = (tid & 15) * 8;        // B col offset

    for (int k0 = 0; k0 < K; k0 += 16) {
        int grow = rowBase + ar;
        float4 a0, a1;
        if (grow < M) {
            const float* ap = A + (long)grow * K + k0 + ah;
            a0 = *(const float4*)ap;
            a1 = *(const float4*)(ap + 4);
        } else {
            a0 = make_float4(0.f, 0.f, 0.f, 0.f);
            a1 = a0;
        }
        const float* bp = W + (long)(k0 + bkk) * Nn + colBase + bc;
        float4 b0 = *(const float4*)bp;
        float4 b1 = *(const float4*)(bp + 4);

        As[ah + 0][ar] = a0.x; As[ah + 1][ar] = a0.y;
        As[ah + 2][ar] = a0.z; As[ah + 3][ar] = a0.w;
        As[ah + 4][ar] = a1.x; As[ah + 5][ar] = a1.y;
        As[ah + 6][ar] = a1.z; As[ah + 7][ar] = a1.w;
        *(float4*)&Bs[bkk][bc]     = b0;
        *(float4*)&Bs[bkk][bc + 4] = b1;
        __syncthreads();

        #pragma unroll
        for (int kk = 0; kk < 16; kk++) {
            float4 xa0 = *(const float4*)&As[kk][ty * 8];
            float4 xa1 = *(const float4*)&As[kk][ty * 8 + 4];
            float4 xb0 = *(const float4*)&Bs[kk][tx * 8];
            float4 xb1 = *(const float4*)&Bs[kk][tx * 8 + 4];
            float av[8] = {xa0.x, xa0.y, xa0.z, xa0.w, xa1.x, xa1.y, xa1.z, xa1.w};
            float bv[8] = {xb0.x, xb0.y, xb0.z, xb0.w, xb1.x, xb1.y, xb1.z, xb1.w};
            #pragma unroll
            for (int i = 0; i < 8; i++)
                #pragma unroll
                for (int j = 0; j < 8; j++)
                    acc[i][j] += av[i] * bv[j];
        }
        __syncthreads();
    }

    #pragma unroll
    for (int i = 0; i < 8; i++) {
        int r = rowBase + ty * 8 + i;
        if (r < M) {
            float* cp = C + (long)r * Nn + colBase + tx * 8;
            *(float4*)cp       = make_float4(acc[i][0], acc[i][1], acc[i][2], acc[i][3]);
            *(float4*)(cp + 4) = make_float4(acc[i][4], acc[i][5], acc[i][6], acc[i][7]);
        }
    }
}

// ---------------- per-node attention scalars ----------------

__global__ void node_alpha(const float* __restrict__ h, const float* __restrict__ attL,
                           const float* __restrict__ attR, float* __restrict__ aL,
                           float* __restrict__ aR) {
    int node = blockIdx.x;
    int t = threadIdx.x;                 // t = head*32 + c
    float hv = h[node * HC + t];
    float pl = hv * attL[t];
    float pr = hv * attR[t];
    #pragma unroll
    for (int s = 16; s; s >>= 1) {
        pl += __shfl_xor(pl, s);
        pr += __shfl_xor(pr, s);
    }
    if ((t & 31) == 0) {
        int head = t >> 5;
        aL[node * HEADS + head] = pl;
        aR[node * HEADS + head] = pr;
    }
}

// ---------------- fused attention: 1 wave per dst node ----------------

__global__ __launch_bounds__(256) void fused_attn(const float* __restrict__ h,
                                                  const int* __restrict__ off,
                                                  const int* __restrict__ esrc,
                                                  const float* __restrict__ aL,
                                                  const float* __restrict__ aR,
                                                  const float* __restrict__ bias,
                                                  float* __restrict__ out,
                                                  int apply_elu) {
    int wave = threadIdx.x >> 6;
    int node = blockIdx.x * 4 + wave;
    if (node >= NNODE) return;
    int l = threadIdx.x & 63;
    int head = l >> 3;
    const float4* h4 = (const float4*)h;

    float4 hi = h4[node * 64 + l];
    float a_ri = aR[node * HEADS + head];
    int beg = off[node], end = off[node + 1];

    float m = -1e30f, lsum = 0.f;
    float4 acc = {0.f, 0.f, 0.f, 0.f};

    int j = esrc[beg];
    for (int p = beg; p < end; ++p) {
        float4 hj = h4[j * 64 + l];
        float a_lj = aL[j * HEADS + head];
        if (p + 1 < end) j = esrc[p + 1];
        float prod = hi.x * hj.x + hi.y * hj.y + hi.z * hj.z + hi.w * hj.w;
        prod += __shfl_xor(prod, 1);
        prod += __shfl_xor(prod, 2);
        prod += __shfl_xor(prod, 4);
        float alpha = (a_lj + a_ri) / (1.f + __expf(-prod));   // * sigmoid
        alpha = (alpha > 0.f) ? alpha : 0.2f * alpha;          // leaky_relu
        float mn = fmaxf(m, alpha);
        float e  = __expf(fminf(m, alpha) - mn);
        bool up = alpha > m;
        float scale = up ? e : 1.f;
        float ex    = up ? 1.f : e;
        lsum = lsum * scale + ex;
        acc.x = acc.x * scale + ex * hj.x;
        acc.y = acc.y * scale + ex * hj.y;
        acc.z = acc.z * scale + ex * hj.z;
        acc.w = acc.w * scale + ex * hj.w;
        m = mn;
    }
    float inv = 1.f / (lsum + 1e-16f);
    float4 b4 = ((const float4*)bias)[l];
    float4 r;
    r.x = acc.x * inv + b4.x;
    r.y = acc.y * inv + b4.y;
    r.z = acc.z * inv + b4.z;
    r.w = acc.w * inv + b4.w;
    if (apply_elu) {
        r.x = (r.x > 0.f) ? r.x : (__expf(r.x) - 1.f);
        r.y = (r.y > 0.f) ? r.y : (__expf(r.y) - 1.f);
        r.z = (r.z > 0.f) ? r.z : (__expf(r.z) - 1.f);
        r.w = (r.w > 0.f) ? r.w : (__expf(r.w) - 1.f);
    }
    ((float4*)out)[node * 64 + l] = r;
}

// ---------------- pooling (segmented, sorted batch) + head ----------------

__global__ __launch_bounds__(256) void pool_kernel(const float* __restrict__ h,
                                                   const int* __restrict__ batch,
                                                   float* __restrict__ psum,
                                                   float* __restrict__ pcnt) {
    int t = threadIdx.x;
    int n0 = blockIdx.x * 64;
    int n1 = min(n0 + 64, NNODE);
    if (n0 >= NNODE) return;
    float accv = 0.f;
    int gcur = batch[n0];
    for (int n = n0; n < n1; ++n) {
        int g = batch[n];
        if (g != gcur) {
            atomicAdd(&psum[gcur * HC + t], accv);
            accv = 0.f;
            gcur = g;
        }
        accv += h[n * HC + t];
    }
    atomicAdd(&psum[gcur * HC + t], accv);
    if (t == 0) {
        int cnt = 0;
        int gc = batch[n0];
        for (int n = n0; n < n1; ++n) {
            int g = batch[n];
            if (g != gc) { atomicAdd(&pcnt[gc], (float)cnt); cnt = 0; gc = g; }
            cnt++;
        }
        atomicAdd(&pcnt[gc], (float)cnt);
    }
}

__global__ void final_kernel(const float* __restrict__ psum, const float* __restrict__ pcnt,
                             const float* __restrict__ linW, const float* __restrict__ linb,
                             float* __restrict__ out) {
    int g = blockIdx.x;
    int t = threadIdx.x;
    __shared__ float p[HC];
    float c = fmaxf(pcnt[g], 1.f);
    p[t] = psum[g * HC + t] / c;
    __syncthreads();
    if (t < NCLS) {
        float s = linb[t];
        for (int cch = 0; cch < HC; cch++) s += p[cch] * linW[cch * NCLS + t];
        out[g * NCLS + t] = s;
    }
}

// ---------------- launch ----------------

extern "C" void kernel_launch(void* const* d_in, const int* in_sizes, int n_in,
                              void* d_out, int out_size, void* d_ws, size_t ws_size,
                              hipStream_t stream) {
    const float* x     = (const float*)d_in[0];
    const int*   ei    = (const int*)d_in[1];
    const int*   batch = (const int*)d_in[2];
    const float* W1    = (const float*)d_in[3];
    const float* attL1 = (const float*)d_in[4];
    const float* attR1 = (const float*)d_in[5];
    const float* b1    = (const float*)d_in[6];
    const float* W2    = (const float*)d_in[7];
    const float* attL2 = (const float*)d_in[8];
    const float* attR2 = (const float*)d_in[9];
    const float* b2    = (const float*)d_in[10];
    const float* linW  = (const float*)d_in[11];
    const float* linb  = (const float*)d_in[12];
    float* out = (float*)d_out;

    // workspace layout
    char* w = (char*)d_ws;
    size_t o = 0;
    int* deg    = (int*)(w + o); o += (size_t)NNODE * 4;
    int* cursor = (int*)(w + o); o += (size_t)NNODE * 4;
    int* off    = (int*)(w + o); o += (size_t)(NNODE + 1) * 4;
    o = (o + 15) & ~(size_t)15;
    int* bsum   = (int*)(w + o); o += (size_t)SCAN_NB * 4;
    int* bscan  = (int*)(w + o); o += (size_t)SCAN_NB * 4;
    o = (o + 15) & ~(size_t)15;
    int* esrc   = (int*)(w + o); o += (size_t)ETOT * 4;
    o = (o + 15) & ~(size_t)15;
    float* bufA = (float*)(w + o); o += (size_t)NNODE * HC * 4;
    float* bufB = (float*)(w + o); o += (size_t)NNODE * HC * 4;
    float* aL   = (float*)(w + o); o += (size_t)NNODE * HEADS * 4;
    float* aR   = (float*)(w + o); o += (size_t)NNODE * HEADS * 4;
    float* psum = (float*)(w + o); o += (size_t)NGRAPH * HC * 4;
    float* pcnt = (float*)(w + o); o += (size_t)NGRAPH * 4;

    hipMemsetAsync(deg, 0, (size_t)2 * NNODE * 4, stream);
    hipMemsetAsync(psum, 0, (size_t)(NGRAPH * HC + NGRAPH) * 4, stream);

    int eb = (ETOT + 255) / 256;
    build_deg<<<eb, 256, 0, stream>>>(ei, deg);
    scan1<<<SCAN_NB, 256, 0, stream>>>(deg, off, bsum);
    scan2<<<1, 128, 0, stream>>>(bsum, bscan, off);
    scan3<<<SCAN_NB, 256, 0, stream>>>(off, bscan);
    scatter_edges<<<eb, 256, 0, stream>>>(ei, off, cursor, esrc);

    dim3 g1((NNODE + 127) / 128, HC / 128);
    int ab = (NNODE + 3) / 4;
    // layer 1
    gemm128<<<g1, 256, 0, stream>>>(x, W1, bufA, NNODE, FIN, HC);
    node_alpha<<<NNODE, 256, 0, stream>>>(bufA, attL1, attR1, aL, aR);
    fused_attn<<<ab, 256, 0, stream>>>(bufA, off, esrc, aL, aR, b1, bufB, 1);
    // layer 2
    gemm128<<<g1, 256, 0, stream>>>(bufB, W2, bufA, NNODE, HC, HC);
    node_alpha<<<NNODE, 256, 0, stream>>>(bufA, attL2, attR2, aL, aR);
    fused_attn<<<ab, 256, 0, stream>>>(bufA, off, esrc, aL, aR, b2, bufB, 0);
    // pool + head
    pool_kernel<<<(NNODE + 63) / 64, 256, 0, stream>>>(bufB, batch, psum, pcnt);
    final_kernel<<<NGRAPH, 256, 0, stream>>>(psum, pcnt, linW, linb, out);
}

// Round 4
// 302.980 us; speedup vs baseline: 2.3914x; 1.2413x over previous
//
#include <hip/hip_runtime.h>
#include <hip/hip_bf16.h>
#include <math.h>

#define NNODE 20000
#define FIN   128
#define HC    256     // HEADS*HID
#define HEADS 8
#define HID   32
#define NEDGE 320000
#define ETOT  (NEDGE + NNODE)
#define NGRAPH 64
#define NCLS  10

#define SCAN_NB ((NNODE + 255) / 256)   // 79

typedef __attribute__((ext_vector_type(8))) short short8v;
typedef __attribute__((ext_vector_type(4))) float float4v;

__device__ __forceinline__ ushort f2bf(float f) {
    __hip_bfloat16 b = __float2bfloat16(f);
    return *(ushort*)&b;
}
__device__ __forceinline__ float bf2f(ushort u) {
    return __uint_as_float(((unsigned)u) << 16);
}

// ---------------- CSR build ----------------

__global__ void build_deg(const int* __restrict__ ei, int* __restrict__ deg) {
    int e = blockIdx.x * blockDim.x + threadIdx.x;
    if (e >= ETOT) return;
    int dst = (e < NEDGE) ? ei[NEDGE + e] : (e - NEDGE);
    atomicAdd(&deg[dst], 1);
}

__global__ __launch_bounds__(256) void scan1(const int* __restrict__ deg,
                                             int* __restrict__ off,
                                             int* __restrict__ bsum) {
    __shared__ int sm[256];
    int i = blockIdx.x * 256 + threadIdx.x;
    int v = (i < NNODE) ? deg[i] : 0;
    sm[threadIdx.x] = v;
    __syncthreads();
    #pragma unroll
    for (int s = 1; s < 256; s <<= 1) {
        int t = (threadIdx.x >= (unsigned)s) ? sm[threadIdx.x - s] : 0;
        __syncthreads();
        sm[threadIdx.x] += t;
        __syncthreads();
    }
    if (i < NNODE) off[i] = sm[threadIdx.x] - v;
    if (threadIdx.x == 255) bsum[blockIdx.x] = sm[255];
}

__global__ __launch_bounds__(128) void scan2(const int* __restrict__ bsum,
                                             int* __restrict__ bscan,
                                             int* __restrict__ off) {
    __shared__ int sm[128];
    int t = threadIdx.x;
    int v = (t < SCAN_NB) ? bsum[t] : 0;
    sm[t] = v;
    __syncthreads();
    #pragma unroll
    for (int s = 1; s < 128; s <<= 1) {
        int u = (t >= (unsigned)s) ? sm[t - s] : 0;
        __syncthreads();
        sm[t] += u;
        __syncthreads();
    }
    if (t < SCAN_NB) bscan[t] = sm[t] - v;
    if (t == SCAN_NB - 1) off[NNODE] = sm[t];
}

__global__ __launch_bounds__(256) void scan3(int* __restrict__ off,
                                             const int* __restrict__ bscan) {
    int i = blockIdx.x * 256 + threadIdx.x;
    if (i < NNODE) off[i] += bscan[blockIdx.x];
}

__global__ void scatter_edges(const int* __restrict__ ei, const int* __restrict__ off,
                              int* __restrict__ cursor, int* __restrict__ esrc) {
    int e = blockIdx.x * blockDim.x + threadIdx.x;
    if (e >= ETOT) return;
    int src, dst;
    if (e < NEDGE) { src = ei[e]; dst = ei[NEDGE + e]; }
    else           { src = e - NEDGE; dst = src; }
    int pos = off[dst] + atomicAdd(&cursor[dst], 1);
    esrc[pos] = src;
}

// ---------------- conversions ----------------

__global__ __launch_bounds__(256) void conv_bf16(const float* __restrict__ src,
                                                 ushort* __restrict__ dst, int n4) {
    int i = blockIdx.x * 256 + threadIdx.x;
    if (i >= n4) return;
    float4 v = ((const float4*)src)[i];
    ushort4 o = { f2bf(v.x), f2bf(v.y), f2bf(v.z), f2bf(v.w) };
    ((ushort4*)dst)[i] = o;
}

// Wt[n][k] = bf16(W[k][n]), N = 256 fixed
__global__ __launch_bounds__(256) void transpose_conv(const float* __restrict__ W,
                                                      ushort* __restrict__ Wt, int K) {
    int e = blockIdx.x * 256 + threadIdx.x;   // e < K*256
    if (e >= K * 256) return;
    int k = e >> 8, n = e & 255;
    Wt[(long)n * K + k] = f2bf(W[(long)k * 256 + n]);
}

// ---------------- bf16 MFMA GEMM: C[M,256] = A[M,K] @ Bt[256,K]^T ------------
// 64x64 block tile, 4 waves x (32x32 quadrant via 2x2 16x16x32 frags), BK=64.

__global__ __launch_bounds__(256) void gemm_mfma(const ushort* __restrict__ A,
                                                 const ushort* __restrict__ Bt,
                                                 ushort* __restrict__ C,
                                                 int M, int K) {
    __shared__ __align__(16) ushort As[64][72];   // pitch 72: 36 dwords -> 2-way max
    __shared__ __align__(16) ushort Bs[64][72];
    int tid = threadIdx.x;
    int rowBase = blockIdx.x * 64;
    int colBase = blockIdx.y * 64;
    int wave = tid >> 6;
    int l = tid & 63;
    int lm = l & 15;
    int quad = l >> 4;
    int r0 = (wave >> 1) * 32;
    int c0 = (wave & 1) * 32;

    float4v acc00 = {0.f, 0.f, 0.f, 0.f};
    float4v acc01 = acc00, acc10 = acc00, acc11 = acc00;

    for (int k0 = 0; k0 < K; k0 += 64) {
        #pragma unroll
        for (int q = 0; q < 2; q++) {
            int ch = tid + q * 256;
            int r  = ch >> 3;
            int kc = (ch & 7) * 8;
            int grow = rowBase + r;
            short8v av = {};
            if (grow < M) av = *(const short8v*)(A + (long)grow * K + k0 + kc);
            *(short8v*)&As[r][kc] = av;
            *(short8v*)&Bs[r][kc] = *(const short8v*)(Bt + (long)(colBase + r) * K + k0 + kc);
        }
        __syncthreads();
        #pragma unroll
        for (int ks = 0; ks < 64; ks += 32) {
            int kb = ks + quad * 8;
            short8v a0 = *(const short8v*)&As[r0 + lm][kb];
            short8v a1 = *(const short8v*)&As[r0 + 16 + lm][kb];
            short8v b0 = *(const short8v*)&Bs[c0 + lm][kb];
            short8v b1 = *(const short8v*)&Bs[c0 + 16 + lm][kb];
            acc00 = __builtin_amdgcn_mfma_f32_16x16x32_bf16(a0, b0, acc00, 0, 0, 0);
            acc01 = __builtin_amdgcn_mfma_f32_16x16x32_bf16(a0, b1, acc01, 0, 0, 0);
            acc10 = __builtin_amdgcn_mfma_f32_16x16x32_bf16(a1, b0, acc10, 0, 0, 0);
            acc11 = __builtin_amdgcn_mfma_f32_16x16x32_bf16(a1, b1, acc11, 0, 0, 0);
        }
        __syncthreads();
    }

    // D mapping (m89/m91 verified): col = lane&15, row = quad*4 + reg
    #pragma unroll
    for (int mi = 0; mi < 2; mi++) {
        float4v s0 = mi ? acc10 : acc00;
        float4v s1 = mi ? acc11 : acc01;
        #pragma unroll
        for (int r = 0; r < 4; r++) {
            int row = rowBase + r0 + mi * 16 + quad * 4 + r;
            if (row < M) {
                C[(long)row * 256 + colBase + c0 + lm]      = f2bf(s0[r]);
                C[(long)row * 256 + colBase + c0 + 16 + lm] = f2bf(s1[r]);
            }
        }
    }
}

// ---------------- per-node attention scalars (bf16 h) ----------------

__global__ void node_alpha(const ushort* __restrict__ h, const float* __restrict__ attL,
                           const float* __restrict__ attR, float* __restrict__ aL,
                           float* __restrict__ aR) {
    int node = blockIdx.x;
    int t = threadIdx.x;                 // t = head*32 + c
    float hv = bf2f(h[node * HC + t]);
    float pl = hv * attL[t];
    float pr = hv * attR[t];
    #pragma unroll
    for (int s = 16; s; s >>= 1) {
        pl += __shfl_xor(pl, s);
        pr += __shfl_xor(pr, s);
    }
    if ((t & 31) == 0) {
        int head = t >> 5;
        aL[node * HEADS + head] = pl;
        aR[node * HEADS + head] = pr;
    }
}

// ---------------- fused attention (bf16 h, bf16 out): 1 wave per dst node ----

__global__ __launch_bounds__(256) void fused_attn(const ushort* __restrict__ h,
                                                  const int* __restrict__ off,
                                                  const int* __restrict__ esrc,
                                                  const float* __restrict__ aL,
                                                  const float* __restrict__ aR,
                                                  const float* __restrict__ bias,
                                                  ushort* __restrict__ out,
                                                  int apply_elu) {
    int wave = threadIdx.x >> 6;
    int node = blockIdx.x * 4 + wave;
    if (node >= NNODE) return;
    int l = threadIdx.x & 63;
    int head = l >> 3;
    const ushort4* h4 = (const ushort4*)h;

    ushort4 hiu = h4[node * 64 + l];
    float4 hi = { bf2f(hiu.x), bf2f(hiu.y), bf2f(hiu.z), bf2f(hiu.w) };
    float a_ri = aR[node * HEADS + head];
    int beg = off[node], end = off[node + 1];

    float m = -1e30f, lsum = 0.f;
    float4 acc = {0.f, 0.f, 0.f, 0.f};

    int j = esrc[beg];
    for (int p = beg; p < end; ++p) {
        ushort4 hju = h4[j * 64 + l];
        float a_lj = aL[j * HEADS + head];
        if (p + 1 < end) j = esrc[p + 1];
        float4 hj = { bf2f(hju.x), bf2f(hju.y), bf2f(hju.z), bf2f(hju.w) };
        float prod = hi.x * hj.x + hi.y * hj.y + hi.z * hj.z + hi.w * hj.w;
        prod += __shfl_xor(prod, 1);
        prod += __shfl_xor(prod, 2);
        prod += __shfl_xor(prod, 4);
        float alpha = (a_lj + a_ri) / (1.f + __expf(-prod));   // * sigmoid
        alpha = (alpha > 0.f) ? alpha : 0.2f * alpha;          // leaky_relu
        float mn = fmaxf(m, alpha);
        float e  = __expf(fminf(m, alpha) - mn);
        bool up = alpha > m;
        float scale = up ? e : 1.f;
        float ex    = up ? 1.f : e;
        lsum = lsum * scale + ex;
        acc.x = acc.x * scale + ex * hj.x;
        acc.y = acc.y * scale + ex * hj.y;
        acc.z = acc.z * scale + ex * hj.z;
        acc.w = acc.w * scale + ex * hj.w;
        m = mn;
    }
    float inv = 1.f / (lsum + 1e-16f);
    float4 b4 = ((const float4*)bias)[l];
    float4 r;
    r.x = acc.x * inv + b4.x;
    r.y = acc.y * inv + b4.y;
    r.z = acc.z * inv + b4.z;
    r.w = acc.w * inv + b4.w;
    if (apply_elu) {
        r.x = (r.x > 0.f) ? r.x : (__expf(r.x) - 1.f);
        r.y = (r.y > 0.f) ? r.y : (__expf(r.y) - 1.f);
        r.z = (r.z > 0.f) ? r.z : (__expf(r.z) - 1.f);
        r.w = (r.w > 0.f) ? r.w : (__expf(r.w) - 1.f);
    }
    ushort4 o = { f2bf(r.x), f2bf(r.y), f2bf(r.z), f2bf(r.w) };
    ((ushort4*)out)[node * 64 + l] = o;
}

// ---------------- pooling (segmented, sorted batch) + head ----------------

__global__ __launch_bounds__(256) void pool_kernel(const ushort* __restrict__ h,
                                                   const int* __restrict__ batch,
                                                   float* __restrict__ psum,
                                                   float* __restrict__ pcnt) {
    int t = threadIdx.x;
    int n0 = blockIdx.x * 64;
    int n1 = min(n0 + 64, NNODE);
    if (n0 >= NNODE) return;
    float accv = 0.f;
    int gcur = batch[n0];
    for (int n = n0; n < n1; ++n) {
        int g = batch[n];
        if (g != gcur) {
            atomicAdd(&psum[gcur * HC + t], accv);
            accv = 0.f;
            gcur = g;
        }
        accv += bf2f(h[n * HC + t]);
    }
    atomicAdd(&psum[gcur * HC + t], accv);
    if (t == 0) {
        int cnt = 0;
        int gc = batch[n0];
        for (int n = n0; n < n1; ++n) {
            int g = batch[n];
            if (g != gc) { atomicAdd(&pcnt[gc], (float)cnt); cnt = 0; gc = g; }
            cnt++;
        }
        atomicAdd(&pcnt[gc], (float)cnt);
    }
}

__global__ void final_kernel(const float* __restrict__ psum, const float* __restrict__ pcnt,
                             const float* __restrict__ linW, const float* __restrict__ linb,
                             float* __restrict__ out) {
    int g = blockIdx.x;
    int t = threadIdx.x;
    __shared__ float p[HC];
    float c = fmaxf(pcnt[g], 1.f);
    p[t] = psum[g * HC + t] / c;
    __syncthreads();
    if (t < NCLS) {
        float s = linb[t];
        for (int cch = 0; cch < HC; cch++) s += p[cch] * linW[cch * NCLS + t];
        out[g * NCLS + t] = s;
    }
}

// ---------------- launch ----------------

extern "C" void kernel_launch(void* const* d_in, const int* in_sizes, int n_in,
                              void* d_out, int out_size, void* d_ws, size_t ws_size,
                              hipStream_t stream) {
    const float* x     = (const float*)d_in[0];
    const int*   ei    = (const int*)d_in[1];
    const int*   batch = (const int*)d_in[2];
    const float* W1    = (const float*)d_in[3];
    const float* attL1 = (const float*)d_in[4];
    const float* attR1 = (const float*)d_in[5];
    const float* b1    = (const float*)d_in[6];
    const float* W2    = (const float*)d_in[7];
    const float* attL2 = (const float*)d_in[8];
    const float* attR2 = (const float*)d_in[9];
    const float* b2    = (const float*)d_in[10];
    const float* linW  = (const float*)d_in[11];
    const float* linb  = (const float*)d_in[12];
    float* out = (float*)d_out;

    // workspace layout
    char* w = (char*)d_ws;
    size_t o = 0;
    int* deg    = (int*)(w + o); o += (size_t)NNODE * 4;
    int* cursor = (int*)(w + o); o += (size_t)NNODE * 4;
    int* off    = (int*)(w + o); o += (size_t)(NNODE + 1) * 4;
    o = (o + 15) & ~(size_t)15;
    int* bsum   = (int*)(w + o); o += (size_t)SCAN_NB * 4;
    int* bscan  = (int*)(w + o); o += (size_t)SCAN_NB * 4;
    o = (o + 15) & ~(size_t)15;
    int* esrc   = (int*)(w + o); o += (size_t)ETOT * 4;
    o = (o + 15) & ~(size_t)15;
    ushort* xb  = (ushort*)(w + o); o += (size_t)NNODE * FIN * 2;
    ushort* W1t = (ushort*)(w + o); o += (size_t)FIN * HC * 2;
    ushort* W2t = (ushort*)(w + o); o += (size_t)HC * HC * 2;
    o = (o + 15) & ~(size_t)15;
    ushort* hbA = (ushort*)(w + o); o += (size_t)NNODE * HC * 2;
    ushort* hbB = (ushort*)(w + o); o += (size_t)NNODE * HC * 2;
    o = (o + 15) & ~(size_t)15;
    float* aL   = (float*)(w + o); o += (size_t)NNODE * HEADS * 4;
    float* aR   = (float*)(w + o); o += (size_t)NNODE * HEADS * 4;
    float* psum = (float*)(w + o); o += (size_t)NGRAPH * HC * 4;
    float* pcnt = (float*)(w + o); o += (size_t)NGRAPH * 4;

    hipMemsetAsync(deg, 0, (size_t)2 * NNODE * 4, stream);
    hipMemsetAsync(psum, 0, (size_t)(NGRAPH * HC + NGRAPH) * 4, stream);

    int eb = (ETOT + 255) / 256;
    build_deg<<<eb, 256, 0, stream>>>(ei, deg);
    scan1<<<SCAN_NB, 256, 0, stream>>>(deg, off, bsum);
    scan2<<<1, 128, 0, stream>>>(bsum, bscan, off);
    scan3<<<SCAN_NB, 256, 0, stream>>>(off, bscan);
    scatter_edges<<<eb, 256, 0, stream>>>(ei, off, cursor, esrc);

    // bf16 conversions
    conv_bf16<<<(NNODE * FIN / 4 + 255) / 256, 256, 0, stream>>>(x, xb, NNODE * FIN / 4);
    transpose_conv<<<FIN, 256, 0, stream>>>(W1, W1t, FIN);
    transpose_conv<<<HC, 256, 0, stream>>>(W2, W2t, HC);

    dim3 gg((NNODE + 63) / 64, HC / 64);
    int ab = (NNODE + 3) / 4;
    // layer 1
    gemm_mfma<<<gg, 256, 0, stream>>>(xb, W1t, hbA, NNODE, FIN);
    node_alpha<<<NNODE, 256, 0, stream>>>(hbA, attL1, attR1, aL, aR);
    fused_attn<<<ab, 256, 0, stream>>>(hbA, off, esrc, aL, aR, b1, hbB, 1);
    // layer 2
    gemm_mfma<<<gg, 256, 0, stream>>>(hbB, W2t, hbA, NNODE, HC);
    node_alpha<<<NNODE, 256, 0, stream>>>(hbA, attL2, attR2, aL, aR);
    fused_attn<<<ab, 256, 0, stream>>>(hbA, off, esrc, aL, aR, b2, hbB, 0);
    // pool + head
    pool_kernel<<<(NNODE + 63) / 64, 256, 0, stream>>>(hbB, batch, psum, pcnt);
    final_kernel<<<NGRAPH, 256, 0, stream>>>(psum, pcnt, linW, linb, out);
}

// Round 5
// 265.155 us; speedup vs baseline: 2.7326x; 1.1427x over previous
//
#include <hip/hip_runtime.h>
#include <hip/hip_bf16.h>
#include <math.h>

#define NNODE 20000
#define FIN   128
#define HC    256     // HEADS*HID
#define HEADS 8
#define HID   32
#define NEDGE 320000
#define ETOT  (NEDGE + NNODE)
#define NGRAPH 64
#define NCLS  10

#define SCAN_NB ((NNODE + 255) / 256)   // 79

typedef __attribute__((ext_vector_type(8))) short short8v;
typedef __attribute__((ext_vector_type(8))) unsigned short ushort8v;
typedef __attribute__((ext_vector_type(4))) float float4v;

__device__ __forceinline__ ushort f2bf(float f) {
    __hip_bfloat16 b = __float2bfloat16(f);
    return *(ushort*)&b;
}
__device__ __forceinline__ float bf2f(ushort u) {
    return __uint_as_float(((unsigned)u) << 16);
}

// ---------------- CSR build ----------------

__global__ void build_deg(const int* __restrict__ ei, int* __restrict__ deg) {
    int e = blockIdx.x * blockDim.x + threadIdx.x;
    if (e >= ETOT) return;
    int dst = (e < NEDGE) ? ei[NEDGE + e] : (e - NEDGE);
    atomicAdd(&deg[dst], 1);
}

__global__ __launch_bounds__(256) void scan1(const int* __restrict__ deg,
                                             int* __restrict__ off,
                                             int* __restrict__ bsum) {
    __shared__ int sm[256];
    int i = blockIdx.x * 256 + threadIdx.x;
    int v = (i < NNODE) ? deg[i] : 0;
    sm[threadIdx.x] = v;
    __syncthreads();
    #pragma unroll
    for (int s = 1; s < 256; s <<= 1) {
        int t = (threadIdx.x >= (unsigned)s) ? sm[threadIdx.x - s] : 0;
        __syncthreads();
        sm[threadIdx.x] += t;
        __syncthreads();
    }
    if (i < NNODE) off[i] = sm[threadIdx.x] - v;
    if (threadIdx.x == 255) bsum[blockIdx.x] = sm[255];
}

__global__ __launch_bounds__(128) void scan2(const int* __restrict__ bsum,
                                             int* __restrict__ bscan,
                                             int* __restrict__ off) {
    __shared__ int sm[128];
    int t = threadIdx.x;
    int v = (t < SCAN_NB) ? bsum[t] : 0;
    sm[t] = v;
    __syncthreads();
    #pragma unroll
    for (int s = 1; s < 128; s <<= 1) {
        int u = (t >= (unsigned)s) ? sm[t - s] : 0;
        __syncthreads();
        sm[t] += u;
        __syncthreads();
    }
    if (t < SCAN_NB) bscan[t] = sm[t] - v;
    if (t == SCAN_NB - 1) off[NNODE] = sm[t];
}

__global__ __launch_bounds__(256) void scan3(int* __restrict__ off,
                                             const int* __restrict__ bscan) {
    int i = blockIdx.x * 256 + threadIdx.x;
    if (i < NNODE) off[i] += bscan[blockIdx.x];
}

__global__ void scatter_edges(const int* __restrict__ ei, const int* __restrict__ off,
                              int* __restrict__ cursor, int* __restrict__ esrc) {
    int e = blockIdx.x * blockDim.x + threadIdx.x;
    if (e >= ETOT) return;
    int src, dst;
    if (e < NEDGE) { src = ei[e]; dst = ei[NEDGE + e]; }
    else           { src = e - NEDGE; dst = src; }
    int pos = off[dst] + atomicAdd(&cursor[dst], 1);
    esrc[pos] = src;
}

// ---------------- W transpose+convert: Wt[n][k] = bf16(W[k][n]), N=256 -------

__global__ __launch_bounds__(256) void transpose_conv(const float* __restrict__ W,
                                                      ushort* __restrict__ Wt, int K) {
    int e = blockIdx.x * 256 + threadIdx.x;
    if (e >= K * 256) return;
    int k = e >> 8, n = e & 255;
    Wt[(long)n * K + k] = f2bf(W[(long)k * 256 + n]);
}

// ---------------- bf16 MFMA GEMM + fused aL/aR epilogue ----------------------
// C[M,256] = A[M,K] @ Bt[256,K]^T. 64x64 tile, 4 waves x 32x32 quadrant, BK=64.
// Epilogue also emits aL[row][head] = sum_c C*attL, aR likewise (no atomics:
// each (row,head) is owned by exactly one wave).

template<bool A_FP32>
__global__ __launch_bounds__(256) void gemm_mfma(const void* __restrict__ Aptr,
                                                 const ushort* __restrict__ Bt,
                                                 ushort* __restrict__ C,
                                                 const float* __restrict__ attL,
                                                 const float* __restrict__ attR,
                                                 float* __restrict__ aL,
                                                 float* __restrict__ aR,
                                                 int M, int K) {
    __shared__ __align__(16) ushort As[64][72];   // pitch 72: 2-way conflicts max (free)
    __shared__ __align__(16) ushort Bs[64][72];
    int tid = threadIdx.x;
    int rowBase = blockIdx.x * 64;
    int colBase = blockIdx.y * 64;
    int wave = tid >> 6;
    int l = tid & 63;
    int lm = l & 15;
    int quad = l >> 4;
    int r0 = (wave >> 1) * 32;
    int c0 = (wave & 1) * 32;

    float4v acc00 = {0.f, 0.f, 0.f, 0.f};
    float4v acc01 = acc00, acc10 = acc00, acc11 = acc00;

    for (int k0 = 0; k0 < K; k0 += 64) {
        if (A_FP32) {
            const float* A = (const float*)Aptr;
            #pragma unroll
            for (int q = 0; q < 4; q++) {
                int idx = tid + q * 256;          // 0..1023 float4 chunks
                int r   = idx >> 4;
                int kc  = (idx & 15) * 4;
                int grow = rowBase + r;
                float4 v = make_float4(0.f, 0.f, 0.f, 0.f);
                if (grow < M) v = *(const float4*)(A + (long)grow * K + k0 + kc);
                ushort4 o = { f2bf(v.x), f2bf(v.y), f2bf(v.z), f2bf(v.w) };
                *(ushort4*)&As[r][kc] = o;
            }
            #pragma unroll
            for (int q = 0; q < 2; q++) {
                int ch = tid + q * 256;
                int r  = ch >> 3;
                int kc = (ch & 7) * 8;
                *(short8v*)&Bs[r][kc] =
                    *(const short8v*)(Bt + (long)(colBase + r) * K + k0 + kc);
            }
        } else {
            const ushort* A = (const ushort*)Aptr;
            #pragma unroll
            for (int q = 0; q < 2; q++) {
                int ch = tid + q * 256;
                int r  = ch >> 3;
                int kc = (ch & 7) * 8;
                int grow = rowBase + r;
                short8v av = {};
                if (grow < M) av = *(const short8v*)(A + (long)grow * K + k0 + kc);
                *(short8v*)&As[r][kc] = av;
                *(short8v*)&Bs[r][kc] =
                    *(const short8v*)(Bt + (long)(colBase + r) * K + k0 + kc);
            }
        }
        __syncthreads();
        #pragma unroll
        for (int ks = 0; ks < 64; ks += 32) {
            int kb = ks + quad * 8;
            short8v a0 = *(const short8v*)&As[r0 + lm][kb];
            short8v a1 = *(const short8v*)&As[r0 + 16 + lm][kb];
            short8v b0 = *(const short8v*)&Bs[c0 + lm][kb];
            short8v b1 = *(const short8v*)&Bs[c0 + 16 + lm][kb];
            acc00 = __builtin_amdgcn_mfma_f32_16x16x32_bf16(a0, b0, acc00, 0, 0, 0);
            acc01 = __builtin_amdgcn_mfma_f32_16x16x32_bf16(a0, b1, acc01, 0, 0, 0);
            acc10 = __builtin_amdgcn_mfma_f32_16x16x32_bf16(a1, b0, acc10, 0, 0, 0);
            acc11 = __builtin_amdgcn_mfma_f32_16x16x32_bf16(a1, b1, acc11, 0, 0, 0);
        }
        __syncthreads();
    }

    // D mapping: col = lane&15, row = quad*4 + reg
    int cb = colBase + c0;            // multiple of 32 -> one head per wave
    int hd = cb >> 5;
    float al0 = attL[cb + lm], al1 = attL[cb + 16 + lm];
    float ar0 = attR[cb + lm], ar1 = attR[cb + 16 + lm];
    #pragma unroll
    for (int mi = 0; mi < 2; mi++) {
        float4v s0 = mi ? acc10 : acc00;
        float4v s1 = mi ? acc11 : acc01;
        #pragma unroll
        for (int r = 0; r < 4; r++) {
            int row = rowBase + r0 + mi * 16 + quad * 4 + r;
            float pl = s0[r] * al0 + s1[r] * al1;
            float pr = s0[r] * ar0 + s1[r] * ar1;
            #pragma unroll
            for (int s2 = 1; s2 < 16; s2 <<= 1) {
                pl += __shfl_xor(pl, s2);     // within 16-lane quad
                pr += __shfl_xor(pr, s2);
            }
            if (row < M) {
                C[(long)row * 256 + cb + lm]      = f2bf(s0[r]);
                C[(long)row * 256 + cb + 16 + lm] = f2bf(s1[r]);
                if (lm == 0) {
                    aL[row * 8 + hd] = pl;
                    aR[row * 8 + hd] = pr;
                }
            }
        }
    }
}

// ---------------- fused attention: 2 nodes/wave, 32 lanes/node, 8 ch/lane ----
// No max-subtraction: alpha is bounded (|alpha| << 88), softmax shift-invariant.

__global__ __launch_bounds__(256) void fused_attn(const ushort* __restrict__ h,
                                                  const int* __restrict__ off,
                                                  const int* __restrict__ esrc,
                                                  const float* __restrict__ aL,
                                                  const float* __restrict__ aR,
                                                  const float* __restrict__ bias,
                                                  ushort* __restrict__ out,
                                                  int apply_elu) {
    int wave = threadIdx.x >> 6;
    int l = threadIdx.x & 63;
    int half = l >> 5;
    int lh = l & 31;                       // lane within node: 8 channels lh*8..
    int node = blockIdx.x * 8 + wave * 2 + half;
    bool valid = node < NNODE;
    int nc = valid ? node : NNODE - 1;
    int head = lh >> 2;                    // 4 lanes per head

    const ushort8v* h8 = (const ushort8v*)h;   // 32 chunks of 8 ch per node
    ushort8v hiu = h8[nc * 32 + lh];
    float hi[8];
    #pragma unroll
    for (int c = 0; c < 8; c++) hi[c] = bf2f(hiu[c]);
    float a_ri = aR[nc * 8 + head];
    int beg = off[nc];
    int end = valid ? off[nc + 1] : beg;
    int deg = end - beg;
    int dmax = max(deg, __shfl_xor(deg, 32));

    float lsum = 0.f;
    float acc[8] = {0.f, 0.f, 0.f, 0.f, 0.f, 0.f, 0.f, 0.f};

    int j = (deg > 0) ? esrc[beg] : 0;
    for (int p = 0; p < dmax; ++p) {
        if (p < deg) {
            ushort8v hju = h8[j * 32 + lh];
            float a_lj = aL[j * 8 + head];
            if (p + 1 < deg) j = esrc[beg + p + 1];
            float hj[8];
            #pragma unroll
            for (int c = 0; c < 8; c++) hj[c] = bf2f(hju[c]);
            float prod = hi[0] * hj[0];
            #pragma unroll
            for (int c = 1; c < 8; c++) prod += hi[c] * hj[c];
            prod += __shfl_xor(prod, 1);   // within 4-lane head group
            prod += __shfl_xor(prod, 2);
            float alpha = (a_lj + a_ri) * __builtin_amdgcn_rcpf(1.f + __expf(-prod));
            alpha = (alpha > 0.f) ? alpha : 0.2f * alpha;      // leaky_relu
            float ex = __expf(alpha);
            lsum += ex;
            #pragma unroll
            for (int c = 0; c < 8; c++) acc[c] += ex * hj[c];
        }
    }

    if (valid) {
        float inv = __builtin_amdgcn_rcpf(lsum + 1e-16f);
        float4 b0 = ((const float4*)bias)[lh * 2];
        float4 b1 = ((const float4*)bias)[lh * 2 + 1];
        float bb[8] = {b0.x, b0.y, b0.z, b0.w, b1.x, b1.y, b1.z, b1.w};
        ushort8v o;
        #pragma unroll
        for (int c = 0; c < 8; c++) {
            float r = acc[c] * inv + bb[c];
            if (apply_elu) r = (r > 0.f) ? r : (__expf(r) - 1.f);
            o[c] = f2bf(r);
        }
        *(ushort8v*)(out + (long)node * 256 + lh * 8) = o;
    }
}

// ---------------- pooling (segmented, sorted batch) + head ----------------

__global__ __launch_bounds__(256) void pool_kernel(const ushort* __restrict__ h,
                                                   const int* __restrict__ batch,
                                                   float* __restrict__ psum,
                                                   float* __restrict__ pcnt) {
    int t = threadIdx.x;
    int n0 = blockIdx.x * 64;
    int n1 = min(n0 + 64, NNODE);
    if (n0 >= NNODE) return;
    float accv = 0.f;
    int gcur = batch[n0];
    for (int n = n0; n < n1; ++n) {
        int g = batch[n];
        if (g != gcur) {
            atomicAdd(&psum[gcur * HC + t], accv);
            accv = 0.f;
            gcur = g;
        }
        accv += bf2f(h[n * HC + t]);
    }
    atomicAdd(&psum[gcur * HC + t], accv);
    if (t == 0) {
        int cnt = 0;
        int gc = batch[n0];
        for (int n = n0; n < n1; ++n) {
            int g = batch[n];
            if (g != gc) { atomicAdd(&pcnt[gc], (float)cnt); cnt = 0; gc = g; }
            cnt++;
        }
        atomicAdd(&pcnt[gc], (float)cnt);
    }
}

__global__ void final_kernel(const float* __restrict__ psum, const float* __restrict__ pcnt,
                             const float* __restrict__ linW, const float* __restrict__ linb,
                             float* __restrict__ out) {
    int g = blockIdx.x;
    int t = threadIdx.x;
    __shared__ float p[HC];
    float c = fmaxf(pcnt[g], 1.f);
    p[t] = psum[g * HC + t] / c;
    __syncthreads();
    if (t < NCLS) {
        float s = linb[t];
        for (int cch = 0; cch < HC; cch++) s += p[cch] * linW[cch * NCLS + t];
        out[g * NCLS + t] = s;
    }
}

// ---------------- launch ----------------

extern "C" void kernel_launch(void* const* d_in, const int* in_sizes, int n_in,
                              void* d_out, int out_size, void* d_ws, size_t ws_size,
                              hipStream_t stream) {
    const float* x     = (const float*)d_in[0];
    const int*   ei    = (const int*)d_in[1];
    const int*   batch = (const int*)d_in[2];
    const float* W1    = (const float*)d_in[3];
    const float* attL1 = (const float*)d_in[4];
    const float* attR1 = (const float*)d_in[5];
    const float* b1    = (const float*)d_in[6];
    const float* W2    = (const float*)d_in[7];
    const float* attL2 = (const float*)d_in[8];
    const float* attR2 = (const float*)d_in[9];
    const float* b2    = (const float*)d_in[10];
    const float* linW  = (const float*)d_in[11];
    const float* linb  = (const float*)d_in[12];
    float* out = (float*)d_out;

    // workspace layout
    char* w = (char*)d_ws;
    size_t o = 0;
    int* deg    = (int*)(w + o); o += (size_t)NNODE * 4;
    int* cursor = (int*)(w + o); o += (size_t)NNODE * 4;
    int* off    = (int*)(w + o); o += (size_t)(NNODE + 1) * 4;
    o = (o + 15) & ~(size_t)15;
    int* bsum   = (int*)(w + o); o += (size_t)SCAN_NB * 4;
    int* bscan  = (int*)(w + o); o += (size_t)SCAN_NB * 4;
    o = (o + 15) & ~(size_t)15;
    int* esrc   = (int*)(w + o); o += (size_t)ETOT * 4;
    o = (o + 15) & ~(size_t)15;
    ushort* W1t = (ushort*)(w + o); o += (size_t)FIN * HC * 2;
    ushort* W2t = (ushort*)(w + o); o += (size_t)HC * HC * 2;
    o = (o + 15) & ~(size_t)15;
    ushort* hbA = (ushort*)(w + o); o += (size_t)NNODE * HC * 2;
    ushort* hbB = (ushort*)(w + o); o += (size_t)NNODE * HC * 2;
    o = (o + 15) & ~(size_t)15;
    float* aL   = (float*)(w + o); o += (size_t)NNODE * HEADS * 4;
    float* aR   = (float*)(w + o); o += (size_t)NNODE * HEADS * 4;
    float* psum = (float*)(w + o); o += (size_t)NGRAPH * HC * 4;
    float* pcnt = (float*)(w + o); o += (size_t)NGRAPH * 4;

    hipMemsetAsync(deg, 0, (size_t)2 * NNODE * 4, stream);
    hipMemsetAsync(psum, 0, (size_t)(NGRAPH * HC + NGRAPH) * 4, stream);

    int eb = (ETOT + 255) / 256;
    build_deg<<<eb, 256, 0, stream>>>(ei, deg);
    scan1<<<SCAN_NB, 256, 0, stream>>>(deg, off, bsum);
    scan2<<<1, 128, 0, stream>>>(bsum, bscan, off);
    scan3<<<SCAN_NB, 256, 0, stream>>>(off, bscan);
    scatter_edges<<<eb, 256, 0, stream>>>(ei, off, cursor, esrc);

    transpose_conv<<<FIN, 256, 0, stream>>>(W1, W1t, FIN);
    transpose_conv<<<HC, 256, 0, stream>>>(W2, W2t, HC);

    dim3 gg((NNODE + 63) / 64, HC / 64);
    int ab = (NNODE + 7) / 8;
    // layer 1 (A = fp32 x, converted during LDS staging)
    gemm_mfma<true><<<gg, 256, 0, stream>>>(x, W1t, hbA, attL1, attR1, aL, aR, NNODE, FIN);
    fused_attn<<<ab, 256, 0, stream>>>(hbA, off, esrc, aL, aR, b1, hbB, 1);
    // layer 2 (A = bf16 h)
    gemm_mfma<false><<<gg, 256, 0, stream>>>(hbB, W2t, hbA, attL2, attR2, aL, aR, NNODE, HC);
    fused_attn<<<ab, 256, 0, stream>>>(hbA, off, esrc, aL, aR, b2, hbB, 0);
    // pool + head
    pool_kernel<<<(NNODE + 63) / 64, 256, 0, stream>>>(hbB, batch, psum, pcnt);
    final_kernel<<<NGRAPH, 256, 0, stream>>>(psum, pcnt, linW, linb, out);
}